// Round 12
// baseline (171.849 us; speedup 1.0000x reference)
//
#include <hip/hip_runtime.h>
#include <hip/hip_fp16.h>

constexpr int N = 50000;        // nodes
constexpr int D = 64;           // feature dim
constexpr int E = 1600000;      // edges
constexpr int NBUCK = (N + 127) / 128;   // 391 buckets of 128 nodes (dst>>7)
constexpr int CAP = 4608;                // bucket window capacity (mean 4092)
constexpr int BTHREADS = 512;
constexpr int CPT = 8;                   // edges per thread in k_bucket
constexpr int EPB = BTHREADS * CPT;      // 4096 edges per block
constexpr int BUCK_BLOCKS = (E + EPB - 1) / EPB;  // 391

// ---------------------------------------------------------------------------
// K0: init per-bucket window cursors (cursor[b] = b*CAP)
__global__ void k_init(int* __restrict__ cursor) {
    int t = threadIdx.x;
    if (t < NBUCK) cursor[t] = t * CAP;
}

// K1: privatized counting-sort scatter -> fixed-capacity bucket windows.
// packed = dst<<16 | src (both < 65536); bucket = packed>>23.
// Edges are permuted into bucket-sorted order in LDS first, so global writes
// are contiguous runs (~21 edges) per bucket chunk instead of full scatter.
__global__ void k_bucket(const int* __restrict__ src, const int* __restrict__ dst,
                         int* __restrict__ cursor, unsigned* __restrict__ packed) {
    __shared__ int lh[NBUCK];
    __shared__ int scan[BTHREADS];
    __shared__ int lb[NBUCK];
    __shared__ unsigned stage[EPB];      // 16 KB
    int tid = threadIdx.x;
    for (int i = tid; i < NBUCK; i += BTHREADS) lh[i] = 0;
    __syncthreads();
    int base_e = blockIdx.x * EPB;
    unsigned pk[CPT];
    int bn[CPT], rk[CPT];
#pragma unroll
    for (int i = 0; i < CPT; ++i) {
        int e = base_e + i * BTHREADS + tid;
        if (e < E) {
            int d = dst[e];
            int s = src[e];
            bn[i] = d >> 7;
            pk[i] = ((unsigned)d << 16) | (unsigned)s;
            rk[i] = atomicAdd(&lh[bn[i]], 1);
        } else bn[i] = -1;
    }
    __syncthreads();
    // inclusive scan of lh over NBUCK (<=512)
    scan[tid] = (tid < NBUCK) ? lh[tid] : 0;
    __syncthreads();
    for (int off = 1; off < BTHREADS; off <<= 1) {
        int v = (tid >= off) ? scan[tid - off] : 0;
        __syncthreads();
        scan[tid] += v;
        __syncthreads();
    }
    if (tid < NBUCK) {
        int c = lh[tid];
        lb[tid] = c ? atomicAdd(&cursor[tid], c) : 0;  // one global atomic per bucket/block
    }
    __syncthreads();
#pragma unroll
    for (int i = 0; i < CPT; ++i) {
        if (bn[i] >= 0) {
            int eb = (bn[i] == 0) ? 0 : scan[bn[i] - 1];
            stage[eb + rk[i]] = pk[i];   // LDS scatter into bucket-sorted order
        }
    }
    __syncthreads();
    int tot = scan[NBUCK - 1];
    for (int j = tid; j < tot; j += BTHREADS) {
        unsigned v = stage[j];
        int bk = v >> 23;                // dst>>7
        int eb = (bk == 0) ? 0 : scan[bk - 1];
        packed[lb[bk] + (j - eb)] = v;   // contiguous within each chunk
    }
}

// K2: one block (512 thr) per 128-node bucket — LDS hist + scan -> rowptr/
// rowend/norm; fill node-sorted u16 src into LDS stage, then coalesced
// uint copy-out to the bucket's CSR window.
__global__ void k_csr(const int* __restrict__ cursor, const unsigned* __restrict__ packed,
                      unsigned short* __restrict__ csr, int* __restrict__ rowptr,
                      int* __restrict__ rowend, float* __restrict__ norm) {
    __shared__ int cnt[128];
    __shared__ int sm[128];
    __shared__ int cur[128];
    __shared__ unsigned short stage[CAP];   // 9 KB
    int b = blockIdx.x, tid = threadIdx.x;
    if (tid < 128) cnt[tid] = 0;
    __syncthreads();
    int beg = b * CAP;
    int m = cursor[b] - beg;                // edges in this bucket
    for (int j = tid; j < m; j += 512)
        atomicAdd(&cnt[(packed[beg + j] >> 16) & 127], 1);
    __syncthreads();
    if (tid < 128) sm[tid] = cnt[tid];
    __syncthreads();
    for (int off = 1; off < 128; off <<= 1) {
        int v = 0;
        if (tid < 128 && tid >= off) v = sm[tid - off];
        __syncthreads();
        if (tid < 128) sm[tid] += v;
        __syncthreads();
    }
    if (tid < 128) {
        int excl = (tid == 0) ? 0 : sm[tid - 1];
        int node = b * 128 + tid;
        if (node < N) {
            rowptr[node] = beg + excl;
            rowend[node] = beg + sm[tid];
            norm[node] = cnt[tid] ? rsqrtf((float)cnt[tid]) : 0.0f;
        }
        cur[tid] = excl;                    // local offset within stage
    }
    __syncthreads();
    for (int j = tid; j < m; j += 512) {
        unsigned p = packed[beg + j];
        int slot = atomicAdd(&cur[(p >> 16) & 127], 1);
        stage[slot] = (unsigned short)(p & 0xFFFFu);
    }
    __syncthreads();
    unsigned* du = (unsigned*)(csr + beg);  // beg even, base 4B-aligned
    const unsigned* su = (const unsigned*)stage;
    int mu = m >> 1;
    for (int k = tid; k < mu; k += 512) du[k] = su[k];
    if ((m & 1) && tid == 0) csr[beg + m - 1] = stage[m - 1];
}

// K3: h2[row][d] = (sum_k x[row][k] * W[k][d]) * norm[row], stored fp16
__global__ void k_gemm(const float* __restrict__ x, const float* __restrict__ W,
                       const float* __restrict__ norm, __half* __restrict__ h2) {
    __shared__ float Wl[64 * 64];
    __shared__ float xs[16][64];
    int tid = threadIdx.x;
    const float4* W4 = (const float4*)W;
    float4* Wl4 = (float4*)Wl;
    Wl4[tid] = W4[tid];
    int r = tid >> 6, d = tid & 63;
    int row = blockIdx.x * 16 + r;
    xs[r][d] = x[row * 64 + d];
    __syncthreads();
    float a = 0.0f;
#pragma unroll
    for (int k = 0; k < 64; ++k) a = fmaf(xs[r][k], Wl[k * 64 + d], a);
    h2[row * 64 + d] = __float2half(a * norm[row]);
}

// K4: fused aggregate + dst-norm + bias + softplus.
// One wave per node. Lane = (edge-slot q=lane>>4, 8B-chunk fl=lane&15): one
// dwordx2 load covers 4 full 128B rows per wave instruction. fp16 packed
// accumulation (v_pk_add_f16) — 1 VALU per half2 instead of cvt2+add2;
// fp32 conversion once in the epilogue. shfl_xor(16/32) combine over edge
// slots; 16 lanes store one float4 each (coalesced 256B row).
__global__ void k_aggregate(const int* __restrict__ rowptr, const int* __restrict__ rowend,
                            const unsigned short* __restrict__ csr,
                            const __half* __restrict__ h2, const float* __restrict__ norm,
                            const float* __restrict__ bias, float* __restrict__ out) {
    int node = blockIdx.x * 4 + (threadIdx.x >> 6);
    int lane = threadIdx.x & 63;
    int q = lane >> 4;             // edge slot 0..3
    int fl = lane & 15;            // 8B chunk -> features 4fl .. 4fl+3
    const uint2* h2v = (const uint2*)h2;   // row stride 16 uint2
    int beg = rowptr[node];
    int end = rowend[node];
    __half2 z = __float2half2_rn(0.0f);
    __half2 a0 = z, a1 = z, b0 = z, b1 = z;
    int j = beg;
    for (; j + 7 < end; j += 8) {          // 8 edges per wave iteration
        int sA = csr[j + q];
        int sB = csr[j + 4 + q];
        uint2 A = h2v[sA * 16 + fl];
        uint2 B = h2v[sB * 16 + fl];
        a0 = __hadd2(a0, __builtin_bit_cast(__half2, A.x));
        a1 = __hadd2(a1, __builtin_bit_cast(__half2, A.y));
        b0 = __hadd2(b0, __builtin_bit_cast(__half2, B.x));
        b1 = __hadd2(b1, __builtin_bit_cast(__half2, B.y));
    }
    if (j < end) {                         // tail (<8 edges), predicated
        int eA = j + q;
        int sA = csr[(eA < end) ? eA : beg];
        uint2 A = h2v[sA * 16 + fl];
        if (eA >= end) { A.x = 0u; A.y = 0u; }
        a0 = __hadd2(a0, __builtin_bit_cast(__half2, A.x));
        a1 = __hadd2(a1, __builtin_bit_cast(__half2, A.y));
        if (j + 4 < end) {
            int eB = j + 4 + q;
            int sB = csr[(eB < end) ? eB : beg];
            uint2 B = h2v[sB * 16 + fl];
            if (eB >= end) { B.x = 0u; B.y = 0u; }
            b0 = __hadd2(b0, __builtin_bit_cast(__half2, B.x));
            b1 = __hadd2(b1, __builtin_bit_cast(__half2, B.y));
        }
    }
    a0 = __hadd2(a0, b0);
    a1 = __hadd2(a1, b1);
    // reduce over the 4 edge slots (strides 16, 32) on half2 bit patterns
    {
        int t0 = __shfl_xor(__builtin_bit_cast(int, a0), 16, 64);
        int t1 = __shfl_xor(__builtin_bit_cast(int, a1), 16, 64);
        a0 = __hadd2(a0, __builtin_bit_cast(__half2, t0));
        a1 = __hadd2(a1, __builtin_bit_cast(__half2, t1));
        t0 = __shfl_xor(__builtin_bit_cast(int, a0), 32, 64);
        t1 = __shfl_xor(__builtin_bit_cast(int, a1), 32, 64);
        a0 = __hadd2(a0, __builtin_bit_cast(__half2, t0));
        a1 = __hadd2(a1, __builtin_bit_cast(__half2, t1));
    }
    if (q == 0) {
        float nrm = norm[node];
        float2 f0 = __half22float2(a0);
        float2 f1 = __half22float2(a1);
        float4 bs = ((const float4*)bias)[fl];
        float v0 = f0.x * nrm + bs.x;
        float v1 = f0.y * nrm + bs.y;
        float v2 = f1.x * nrm + bs.z;
        float v3 = f1.y * nrm + bs.w;
        float4 o;
        o.x = fmaxf(v0, 0.0f) + log1pf(expf(-fabsf(v0)));
        o.y = fmaxf(v1, 0.0f) + log1pf(expf(-fabsf(v1)));
        o.z = fmaxf(v2, 0.0f) + log1pf(expf(-fabsf(v2)));
        o.w = fmaxf(v3, 0.0f) + log1pf(expf(-fabsf(v3)));
        ((float4*)out)[node * 16 + fl] = o;
    }
}

extern "C" void kernel_launch(void* const* d_in, const int* in_sizes, int n_in,
                              void* d_out, int out_size, void* d_ws, size_t ws_size,
                              hipStream_t stream) {
    // inputs: t(f32,1), x(f32,N*D), weight(f32,D*D), bias(f32,D), src(i32,E), dst(i32,E)
    const float* x    = (const float*)d_in[1];
    const float* W    = (const float*)d_in[2];
    const float* bias = (const float*)d_in[3];
    const int* src = (const int*)d_in[4];
    const int* dst = (const int*)d_in[5];
    float* out = (float*)d_out;

    // workspace layout (~17.9 MB; poisoned 0xAA every call — every buffer is
    // fully written before it is read)
    char* ws = (char*)d_ws;
    __half*         h2     = (__half*)(ws);                     // 6.4 MB
    unsigned*       packed = (unsigned*)(ws + 6400000);         // NBUCK*CAP*4 = 7.21 MB
    unsigned short* csr    = (unsigned short*)(ws + 13606912);  // NBUCK*CAP*2 = 3.6 MB
    int*            rowptr = (int*)(ws + 17210368);             // N*4
    int*            rowend = (int*)(ws + 17410368);             // N*4
    float*          norm   = (float*)(ws + 17610368);           // N*4
    int*            cursor = (int*)(ws + 17810368);             // NBUCK*4

    k_init     <<<1, 512, 0, stream>>>(cursor);
    k_bucket   <<<BUCK_BLOCKS, BTHREADS, 0, stream>>>(src, dst, cursor, packed);
    k_csr      <<<NBUCK, 512, 0, stream>>>(cursor, packed, csr, rowptr, rowend, norm);
    k_gemm     <<<(N + 15) / 16, 1024, 0, stream>>>(x, W, norm, h2);
    k_aggregate<<<(N + 3) / 4, 256, 0, stream>>>(rowptr, rowend, csr, h2, norm, bias, out);
}